// Round 3
// baseline (335.510 us; speedup 1.0000x reference)
//
#include <hip/hip_runtime.h>
#include <cstdint>
#include <math.h>

typedef __bf16 bf16_t;
typedef __bf16 bf16x8 __attribute__((ext_vector_type(8)));
typedef __bf16 bf16x4 __attribute__((ext_vector_type(4)));
typedef float f32x4 __attribute__((ext_vector_type(4)));

#define MFMA16(a, b, c) __builtin_amdgcn_mfma_f32_16x16x32_bf16((a), (b), (c), 0, 0, 0)

static constexpr int BATCH = 4;
static constexpr int SEQ = 2048;
static constexpr int DIMC = 1024;
static constexpr int NH = 16;
static constexpr int HD = 64;

__device__ __forceinline__ void async_copy16(void* lds, const void* g) {
    __builtin_amdgcn_global_load_lds(
        (const __attribute__((address_space(1))) void*)g,
        (__attribute__((address_space(3))) void*)lds, 16, 0, 0);
}

__device__ __forceinline__ float fast_exp2(float x) {
#if __has_builtin(__builtin_amdgcn_exp2f)
    return __builtin_amdgcn_exp2f(x);
#else
    return __expf(x * 0.6931471805599453f);
#endif
}

// ---------------- fp32 -> bf16 elementwise convert, 3 tensors -----------------
__global__ __launch_bounds__(256) void cvt3(const float* __restrict__ q,
                                            const float* __restrict__ k,
                                            const float* __restrict__ v,
                                            bf16_t* __restrict__ out) {
    const float* in = (blockIdx.y == 0) ? q : ((blockIdx.y == 1) ? k : v);
    bf16_t* o = out + (size_t)blockIdx.y * BATCH * SEQ * DIMC;
    const int i = blockIdx.x * 256 + threadIdx.x;  // 8 elems per thread
    const float4 f0 = ((const float4*)in)[i * 2];
    const float4 f1 = ((const float4*)in)[i * 2 + 1];
    bf16x8 vv;
    vv[0] = (bf16_t)f0.x; vv[1] = (bf16_t)f0.y; vv[2] = (bf16_t)f0.z; vv[3] = (bf16_t)f0.w;
    vv[4] = (bf16_t)f1.x; vv[5] = (bf16_t)f1.y; vv[6] = (bf16_t)f1.z; vv[7] = (bf16_t)f1.w;
    ((bf16x8*)o)[i] = vv;
}

// ---------------- weight transpose + fp32->bf16 convert -----------------
__global__ __launch_bounds__(256) void transpose_cvt(const float* __restrict__ W0,
                                                     const float* __restrict__ W1,
                                                     const float* __restrict__ W2,
                                                     const float* __restrict__ W3,
                                                     bf16_t* __restrict__ out) {
    const float* Ws[4] = {W0, W1, W2, W3};
    const float* W = Ws[blockIdx.z];
    bf16_t* Wt = out + (size_t)blockIdx.z * DIMC * DIMC;
    __shared__ float tile[32][33];
    const int tx = threadIdx.x & 31;
    const int ty = threadIdx.x >> 5;
    const int x0 = blockIdx.x * 32;
    const int y0 = blockIdx.y * 32;
    #pragma unroll
    for (int j = ty; j < 32; j += 8)
        tile[j][tx] = W[(size_t)(y0 + j) * DIMC + x0 + tx];
    __syncthreads();
    #pragma unroll
    for (int j = ty; j < 32; j += 8)
        Wt[(size_t)(x0 + j) * DIMC + y0 + tx] = (bf16_t)tile[tx][j];
}

// ---------------- rope tables -----------------
__global__ __launch_bounds__(256) void rope_tab(float* __restrict__ cosT, float* __restrict__ sinT) {
    const int idx = blockIdx.x * 256 + threadIdx.x;  // 65536 = 2048*32
    const int t = idx >> 5;
    const int p = idx & 31;
    const float inv = exp2f(-0.41524101186092029f * (float)p);
    const float ang = (float)t * inv;
    float s, c;
    sincosf(ang, &s, &c);
    cosT[idx] = c;
    sinT[idx] = s;
}

// ===== 256-col GEMM core: BN=256, BK=32, 8 waves (2x4), QUAD-buffered LDS,
// 3-tiles-ahead global_load_lds staging, counted vmcnt, 1 raw s_barrier/K-tile.
// MI = m-frags per wave (8 -> BM=256, 4 -> BM=128). Per-wave output MI*16 x 64.
// LDS swizzle: element (row r, 16B-granule g) at r*64B + ((g ^ f(r&15))*16B),
// f(r)=(r&3)^((r>>2)&3).
// Pipeline safety (buffers mod 4, stage t+3 at iter t, after the barrier):
//  - buf[(t+3)%4]=buf[(t-1)%4]: all waves' ds_reads of buf t-1 are lgkm-drained
//    before their iter-(t-1) MFMAs issue, hence before they reach the iter-t
//    barrier, hence before any wave issues the t+3 DMA.
//  - tile-t DMA completion before reads: own loads via counted vmcnt
//    (outstanding newer = 2 tiles * LPT), other waves' via the barrier placed
//    after every wave's own vmcnt wait.
template <int MI>
__device__ __forceinline__ void gemm_core(const bf16_t* __restrict__ A,
                                          const bf16_t* __restrict__ Bt,
                                          const int row0, const int col0,
                                          bf16_t* As, bf16_t* Bs, const int tid,
                                          f32x4 (&acc)[MI][4]) {
    constexpr int ABUF = MI * 32 * 32;  // elems per A buffer (8192 / 4096)
    constexpr int BBUF = 256 * 32;      // 8192
    constexpr int NT = DIMC / 32;       // 32 K-tiles
    const int wid = tid >> 6;
    const int lane = tid & 63;
    const int l15 = lane & 15;
    const int quad = lane >> 4;
    const int wr = wid >> 2;  // 0..1
    const int wc = wid & 3;   // 0..3
    const int rIn = lane >> 2;
    const int gW = ((lane & 3) ^ ((rIn & 3) ^ ((rIn >> 2) & 3))) * 8;
    const int fR = (l15 & 3) ^ ((l15 >> 2) & 3);

#define STAGE_TILE(bi, kt)                                                              \
    {                                                                                   \
        const int k0_ = (kt)*32;                                                        \
        bf16_t* as_ = As + (bi)*ABUF;                                                   \
        bf16_t* bs_ = Bs + (bi)*BBUF;                                                   \
        if constexpr (MI == 8) {                                                        \
            _Pragma("unroll") for (int ci = 0; ci < 2; ++ci) {                          \
                const int c = 2 * wid + ci;                                             \
                async_copy16(&as_[c * 512],                                             \
                             A + (size_t)(row0 + c * 16 + rIn) * DIMC + k0_ + gW);      \
            }                                                                           \
        } else {                                                                        \
            async_copy16(&as_[wid * 512],                                               \
                         A + (size_t)(row0 + wid * 16 + rIn) * DIMC + k0_ + gW);        \
        }                                                                               \
        _Pragma("unroll") for (int ci = 0; ci < 2; ++ci) {                              \
            const int c = 2 * wid + ci;                                                 \
            async_copy16(&bs_[c * 512],                                                 \
                         Bt + (size_t)(col0 + c * 16 + rIn) * DIMC + k0_ + gW);         \
        }                                                                               \
    }

    STAGE_TILE(0, 0)
    STAGE_TILE(1, 1)
    STAGE_TILE(2, 2)
    int rb = 0;
    for (int t = 0; t < NT; ++t) {
        const int rem = NT - 1 - t;
        if constexpr (MI == 8) {  // 4 loads/tile/wave
            if (rem >= 2) asm volatile("s_waitcnt vmcnt(8)" ::: "memory");
            else if (rem == 1) asm volatile("s_waitcnt vmcnt(4)" ::: "memory");
            else asm volatile("s_waitcnt vmcnt(0)" ::: "memory");
        } else {  // 3 loads/tile/wave
            if (rem >= 2) asm volatile("s_waitcnt vmcnt(6)" ::: "memory");
            else if (rem == 1) asm volatile("s_waitcnt vmcnt(3)" ::: "memory");
            else asm volatile("s_waitcnt vmcnt(0)" ::: "memory");
        }
        asm volatile("s_barrier" ::: "memory");
        if (t + 3 < NT) {
            int sb = rb + 3;
            if (sb >= 4) sb -= 4;
            STAGE_TILE(sb, t + 3)
        }
        const bf16_t* as = As + rb * ABUF;
        const bf16_t* bs = Bs + rb * BBUF;
        bf16x8 bfrag[4];
        #pragma unroll
        for (int ni = 0; ni < 4; ++ni)
            bfrag[ni] = *(const bf16x8*)&bs[(wc * 64 + ni * 16 + l15) * 32 + ((quad ^ fR) << 3)];
        bf16x8 afrag[MI];
        #pragma unroll
        for (int mi = 0; mi < MI; ++mi)
            afrag[mi] =
                *(const bf16x8*)&as[(wr * (MI * 16) + mi * 16 + l15) * 32 + ((quad ^ fR) << 3)];
        __builtin_amdgcn_s_setprio(1);
        #pragma unroll
        for (int mi = 0; mi < MI; ++mi)
            #pragma unroll
            for (int ni = 0; ni < 4; ++ni)
                acc[mi][ni] = MFMA16(afrag[mi], bfrag[ni], acc[mi][ni]);
        __builtin_amdgcn_s_setprio(0);
        rb = (rb + 1) & 3;
    }
#undef STAGE_TILE
}

// ---------------- fused QKV GEMM (256x256 tile, 512 thr) -----------------
// Grid (x=row-panel 32, y=col 4, z=3): linear id = x + 32y + 128z, so
// dispatch%8 = x%8 — all 4 col-blocks of a row-panel (and its 3 z's) share one
// XCD: A re-reads and the 2MB weight panel are L2-local (round-1's locality).
// z selects (A, W, bias, out). Q (z==0) pre-scaled by 0.125*log2(e).
__global__ __launch_bounds__(512, 2) void gemm_qkv(const bf16_t* __restrict__ Cb,
                                                   const bf16_t* __restrict__ Wt3,
                                                   const float* __restrict__ bq,
                                                   const float* __restrict__ bk,
                                                   const float* __restrict__ bv,
                                                   bf16_t* __restrict__ Qr,
                                                   bf16_t* __restrict__ Kr,
                                                   bf16_t* __restrict__ Vr,
                                                   const float* __restrict__ cosT,
                                                   const float* __restrict__ sinT) {
    __shared__ __align__(16) unsigned char smem[131072];  // 4x16KB A + 4x16KB B
    bf16_t* As = (bf16_t*)smem;
    bf16_t* Bs = (bf16_t*)(smem + 65536);
    float* eps = (float*)smem;  // epilogue alias: 32 x 264 fp32 = 33.8KB
    const int z = blockIdx.z;
    const bf16_t* A = Cb + (size_t)z * BATCH * SEQ * DIMC;
    const bf16_t* Bt = Wt3 + (size_t)z * DIMC * DIMC;
    const float* bias = (z == 0) ? bq : ((z == 1) ? bk : bv);
    bf16_t* outp = (z == 0) ? Qr : ((z == 1) ? Kr : Vr);
    const bool rope = (z < 2);
    const int tid = threadIdx.x;
    const int row0 = blockIdx.x * 256, col0 = blockIdx.y * 256;
    f32x4 acc[8][4] = {};
    gemm_core<8>(A, Bt, row0, col0, As, Bs, tid, acc);

    const int wid = tid >> 6;
    const int lane = tid & 63;
    const int l15 = lane & 15;
    const int quad = lane >> 4;
    const int wr = wid >> 2, wc = wid & 3;
    float bvl[4];
    #pragma unroll
    for (int ni = 0; ni < 4; ++ni) bvl[ni] = bias[col0 + wc * 64 + ni * 16 + l15];
    // read-phase mapping: 512 threads = 32 rows x 16 col-groups of 16
    const int lr = tid >> 4;
    const int cg = tid & 15;
    const int c0 = cg * 16;
    const int h = (col0 + c0) >> 6;
    const int dbase = c0 & 63;
    const float osc = (z == 0) ? 0.18033688011112043f : 1.0f;
    #pragma unroll
    for (int p = 0; p < 8; ++p) {  // p = mi slab: rows {wr*128 + p*16 + 0..15}
        __syncthreads();
        #pragma unroll
        for (int ni = 0; ni < 4; ++ni)
            #pragma unroll
            for (int r = 0; r < 4; ++r)
                eps[(wr * 16 + quad * 4 + r) * 264 + wc * 64 + ni * 16 + l15] =
                    acc[p][ni][r] + bvl[ni];
        __syncthreads();
        const int grow = row0 + (lr >> 4) * 128 + p * 16 + (lr & 15);
        const int tq = grow & (SEQ - 1);
        const int bb = grow >> 11;
        float vals[16];
        #pragma unroll
        for (int q4 = 0; q4 < 4; ++q4) {
            f32x4 vv = *(const f32x4*)&eps[lr * 264 + c0 + q4 * 4];
            vals[q4 * 4 + 0] = vv[0]; vals[q4 * 4 + 1] = vv[1];
            vals[q4 * 4 + 2] = vv[2]; vals[q4 * 4 + 3] = vv[3];
        }
        bf16x8 o0, o1;
        if (rope) {
            const int pbase = tq * 32 + (dbase >> 1);
            const float4 cs0 = *(const float4*)&cosT[pbase];
            const float4 cs1 = *(const float4*)&cosT[pbase + 4];
            const float4 sn0 = *(const float4*)&sinT[pbase];
            const float4 sn1 = *(const float4*)&sinT[pbase + 4];
            const float cc[8] = {cs0.x, cs0.y, cs0.z, cs0.w, cs1.x, cs1.y, cs1.z, cs1.w};
            const float ss[8] = {sn0.x, sn0.y, sn0.z, sn0.w, sn1.x, sn1.y, sn1.z, sn1.w};
            #pragma unroll
            for (int i = 0; i < 8; ++i) {
                const float e = vals[2 * i], o = vals[2 * i + 1];
                const float oe = (e * cc[i] - o * ss[i]) * osc;
                const float oo = (e * ss[i] + o * cc[i]) * osc;
                if (i < 4) { o0[2 * i] = (bf16_t)oe; o0[2 * i + 1] = (bf16_t)oo; }
                else { o1[2 * (i - 4)] = (bf16_t)oe; o1[2 * (i - 4) + 1] = (bf16_t)oo; }
            }
        } else {
            #pragma unroll
            for (int i = 0; i < 8; ++i) o0[i] = (bf16_t)vals[i];
            #pragma unroll
            for (int i = 0; i < 8; ++i) o1[i] = (bf16_t)vals[8 + i];
        }
        bf16_t* dst = outp + (((size_t)bb * NH + h) * SEQ + tq) * HD + dbase;
        *(bf16x8*)dst = o0;
        *(bf16x8*)(dst + 8) = o1;
    }
}

// ---------------- output GEMM (128x256 tile, fp32 out) -----------------
// Grid (x=row-panel 64, y=col 4): 256 blocks = exactly 1/CU; dispatch%8 = x%8
// keeps all 4 col-blocks of a row-panel on one XCD.
__global__ __launch_bounds__(512, 2) void gemm_o(const bf16_t* __restrict__ A,
                                                 const bf16_t* __restrict__ Bt,
                                                 const float* __restrict__ bias,
                                                 float* __restrict__ out) {
    __shared__ __align__(16) unsigned char smem[98304];  // 4x8KB A + 4x16KB B
    bf16_t* As = (bf16_t*)smem;
    bf16_t* Bs = (bf16_t*)(smem + 32768);
    const int tid = threadIdx.x;
    const int row0 = blockIdx.x * 128, col0 = blockIdx.y * 256;
    f32x4 acc[4][4] = {};
    gemm_core<4>(A, Bt, row0, col0, As, Bs, tid, acc);
    const int wid = tid >> 6;
    const int lane = tid & 63;
    const int l15 = lane & 15;
    const int quad = lane >> 4;
    const int wr = wid >> 2, wc = wid & 3;
    #pragma unroll
    for (int ni = 0; ni < 4; ++ni) {
        const int col = col0 + wc * 64 + ni * 16 + l15;
        const float bvl = bias[col];
        #pragma unroll
        for (int mi = 0; mi < 4; ++mi) {
            #pragma unroll
            for (int r = 0; r < 4; ++r) {
                const int row = row0 + wr * 64 + mi * 16 + quad * 4 + r;
                out[(size_t)row * DIMC + col] = acc[mi][ni][r] + bvl;
            }
        }
    }
}

// ---------------- flash attention (causal, no-max softmax, S^T trick) -----------------
// Qr/Kr/Vr: bf16 [B,H,S,64] (rope on Q,K; Q pre-scaled by 0.125*log2e). O: bf16 [B*S,1024]
// Single-barrier software pipeline, Ks/Vt double-buffered (see round-1 notes).
__global__ __launch_bounds__(256) void attn_kernel(const bf16_t* __restrict__ Qr,
                                                   const bf16_t* __restrict__ Kr,
                                                   const bf16_t* __restrict__ Vr,
                                                   bf16_t* __restrict__ O) {
    __shared__ bf16_t Ks[2][64 * 64];   // swizzled [s][d], double-buffered (16 KB)
    __shared__ bf16_t Vt[2][64 * 72];   // [d][s] stride 72, double-buffered (18 KB)
    __shared__ bf16_t Ps[4][32 * 72];   // per-wave [t-local][s], stride 72 (18 KB)
    const int tid = threadIdx.x;
    const int w = tid >> 6;
    const int lane = tid & 63;
    const int l15 = lane & 15;
    const int quad = lane >> 4;
    const int bh = blockIdx.x;
    const int b = bh >> 4, h = bh & 15;
    const bf16_t* Qb = Qr + (size_t)bh * SEQ * HD;
    const bf16_t* Kb = Kr + (size_t)bh * SEQ * HD;
    const bf16_t* Vb = Vr + (size_t)bh * SEQ * HD;

    bf16x8 ones;
    #pragma unroll
    for (int j8 = 0; j8 < 8; ++j8) ones[j8] = (bf16_t)1.0f;
    bf16x8 idB[2];
    #pragma unroll
    for (int ch = 0; ch < 2; ++ch)
        #pragma unroll
        for (int j8 = 0; j8 < 8; ++j8)
            idB[ch][j8] = (quad * 8 + j8 == ch * 16 + l15) ? (bf16_t)1.0f : (bf16_t)0.0f;

    const int sIn = lane >> 3;              // s within chunk
    const int gK = ((lane & 7) ^ sIn) * 8;  // swizzled source d-offset
    const int fK = (l15 & 7);               // read-side swizzle key

#define VTRANS(buf, a0, a1)                                                      \
    {                                                                            \
        _Pragma("unroll") for (int c = 0; c < 4; ++c) {                          \
            f32x4 zt = {};                                                       \
            f32x4 tv = MFMA16((c < 2) ? (a0) : (a1), idB[c & 1], zt);            \
            bf16x4 pkt;                                                          \
            _Pragma("unroll") for (int rr = 0; rr < 4; ++rr)                     \
                pkt[rr] = (bf16_t)tv[rr];                                        \
            *(bf16x4*)&Vt[buf][(c * 16 + l15) * 72 + w * 16 + quad * 4] = pkt;   \
        }                                                                        \
    }

    const int j = 15 - (int)blockIdx.y;  // big tiles first (LPT)
    const int q0 = j * 128;
    bf16x8 qa[2][2];
    #pragma unroll
    for (int mg = 0; mg < 2; ++mg)
        #pragma unroll
        for (int kc = 0; kc < 2; ++kc)
            qa[mg][kc] = *(const bf16x8*)(Qb + (size_t)(q0 + mg * 64 + w * 16 + l15) * HD +
                                          kc * 32 + quad * 8);
    f32x4 acco[2][4] = {};
    f32x4 accl[2] = {};
    const int nIter = 2 * j + 2;

    #pragma unroll
    for (int ci = 0; ci < 2; ++ci) {
        const int c = 2 * w + ci;
        async_copy16(&Ks[0][c * 512], Kb + (size_t)(c * 8 + sIn) * HD + gK);
    }
    {
        const bf16_t* vsrc = Vb + (size_t)(w * 16 + l15) * HD + quad * 8;
        bf16x8 pv0 = *(const bf16x8*)vsrc;
        bf16x8 pv1 = *(const bf16x8*)(vsrc + 32);
        VTRANS(0, pv0, pv1);
    }
    __syncthreads();

    int cur = 0;
    for (int it = 0; it < nIter; ++it) {
        const int nxt = cur ^ 1;
        const bool hn = (it + 1 < nIter);
        bf16x8 av0, av1;
        if (hn) {
            const int s1 = (it + 1) * 64;
            #pragma unroll
            for (int ci = 0; ci < 2; ++ci) {
                const int c = 2 * w + ci;
                async_copy16(&Ks[nxt][c * 512], Kb + (size_t)(s1 + c * 8 + sIn) * HD + gK);
            }
            const bf16_t* vsrc = Vb + (size_t)(s1 + w * 16 + l15) * HD + quad * 8;
            av0 = *(const bf16x8*)vsrc;
            av1 = *(const bf16x8*)(vsrc + 32);
        }
        bf16x8 kb[4][2];
        #pragma unroll
        for (int mt = 0; mt < 4; ++mt)
            #pragma unroll
            for (int kc = 0; kc < 2; ++kc)
                kb[mt][kc] = *(const bf16x8*)&Ks[cur][(mt * 16 + l15) * 64 +
                                                      (((kc * 4 + quad) ^ fK) << 3)];
        const bool skip0 = (it == 2 * j + 1);
        f32x4 zz[2][4];
        __builtin_amdgcn_s_setprio(1);
        #pragma unroll
        for (int mg = 0; mg < 2; ++mg) {
            if (mg == 0 && skip0) continue;
            #pragma unroll
            for (int mt = 0; mt < 4; ++mt) {
                f32x4 z = {};
                z = MFMA16(kb[mt][0], qa[mg][0], z);
                z = MFMA16(kb[mt][1], qa[mg][1], z);
                zz[mg][mt] = z;
            }
        }
        __builtin_amdgcn_s_setprio(0);
        #pragma unroll
        for (int mg = 0; mg < 2; ++mg) {
            if (mg == 0 && skip0) continue;
            const bool diag = (it == 2 * j + mg);
            #pragma unroll
            for (int mt = 0; mt < 4; ++mt) {
                bf16x4 pk;
                #pragma unroll
                for (int r = 0; r < 4; ++r) {
                    float v = zz[mg][mt][r];
                    if (diag && (mt * 16 + quad * 4 + r > w * 16 + l15)) v = -INFINITY;
                    pk[r] = (bf16_t)fast_exp2(v);
                }
                *(bf16x4*)&Ps[w][(mg * 16 + l15) * 72 + mt * 16 + quad * 4] = pk;
            }
        }
        asm volatile("s_waitcnt lgkmcnt(0)" ::: "memory");
        bf16x8 vb[4][2];
        #pragma unroll
        for (int dt = 0; dt < 4; ++dt)
            #pragma unroll
            for (int kc = 0; kc < 2; ++kc)
                vb[dt][kc] = *(const bf16x8*)&Vt[cur][(dt * 16 + l15) * 72 + kc * 32 + quad * 8];
        #pragma unroll
        for (int mg = 0; mg < 2; ++mg) {
            if (mg == 0 && skip0) continue;
            const bf16x8 pa0 = *(const bf16x8*)&Ps[w][(mg * 16 + l15) * 72 + quad * 8];
            const bf16x8 pa1 = *(const bf16x8*)&Ps[w][(mg * 16 + l15) * 72 + 32 + quad * 8];
            __builtin_amdgcn_s_setprio(1);
            #pragma unroll
            for (int dt = 0; dt < 4; ++dt) {
                acco[mg][dt] = MFMA16(pa0, vb[dt][0], acco[mg][dt]);
                acco[mg][dt] = MFMA16(pa1, vb[dt][1], acco[mg][dt]);
            }
            accl[mg] = MFMA16(pa0, ones, accl[mg]);
            accl[mg] = MFMA16(pa1, ones, accl[mg]);
            __builtin_amdgcn_s_setprio(0);
        }
        if (hn) VTRANS(nxt, av0, av1);
        __syncthreads();
        cur = nxt;
    }
    #pragma unroll
    for (int mg = 0; mg < 2; ++mg) {
        #pragma unroll
        for (int r = 0; r < 4; ++r) {
            const float inv = 1.0f / accl[mg][r];
            const int trow = q0 + mg * 64 + w * 16 + quad * 4 + r;
            bf16_t* orow = O + ((size_t)(b * SEQ + trow)) * DIMC + h * HD;
            #pragma unroll
            for (int dt = 0; dt < 4; ++dt)
                orow[dt * 16 + l15] = (bf16_t)(acco[mg][dt][r] * inv);
        }
    }
#undef VTRANS
}

extern "C" void kernel_launch(void* const* d_in, const int* in_sizes, int n_in,
                              void* d_out, int out_size, void* d_ws, size_t ws_size,
                              hipStream_t stream) {
    const float* query = (const float*)d_in[0];
    const float* key = (const float*)d_in[1];
    const float* value = (const float*)d_in[2];
    const float* Wq = (const float*)d_in[3];
    const float* bq = (const float*)d_in[4];
    const float* Wk = (const float*)d_in[5];
    const float* bk = (const float*)d_in[6];
    const float* Wv = (const float*)d_in[7];
    const float* bv = (const float*)d_in[8];
    const float* Wo = (const float*)d_in[9];
    const float* bo = (const float*)d_in[10];

    char* ws = (char*)d_ws;
    const size_t WT_BYTES = (size_t)DIMC * DIMC * sizeof(bf16_t);          // 2 MB
    const size_t ACT_BYTES = (size_t)BATCH * SEQ * DIMC * sizeof(bf16_t);  // 16 MB
    bf16_t* WT = (bf16_t*)ws;  // WqT,WkT,WvT,WoT consecutive (8 MB)
    bf16_t* WoT = WT + 3 * (size_t)DIMC * DIMC;
    float* cosT = (float*)(ws + 4 * WT_BYTES);
    float* sinT = (float*)(ws + 4 * WT_BYTES + 262144);
    bf16_t* Cb = (bf16_t*)(ws + 4 * WT_BYTES + 2 * 262144);  // 3x16 MB bf16 inputs
    bf16_t* Qr = (bf16_t*)((char*)Cb + 3 * ACT_BYTES);
    bf16_t* Kr = (bf16_t*)((char*)Cb + 4 * ACT_BYTES);
    bf16_t* Vr = (bf16_t*)((char*)Cb + 5 * ACT_BYTES);
    bf16_t* Ob = Cb;  // attention output aliases Cq (free after QKV GEMMs)

    transpose_cvt<<<dim3(32, 32, 4), 256, 0, stream>>>(Wq, Wk, Wv, Wo, WT);
    rope_tab<<<dim3(256), 256, 0, stream>>>(cosT, sinT);
    cvt3<<<dim3(4096, 3), 256, 0, stream>>>(query, key, value, Cb);
    gemm_qkv<<<dim3((BATCH * SEQ) / 256, DIMC / 256, 3), 512, 0, stream>>>(
        Cb, WT, bq, bk, bv, Qr, Kr, Vr, cosT, sinT);
    attn_kernel<<<dim3(BATCH * NH, 16), 256, 0, stream>>>(Qr, Kr, Vr, Ob);
    gemm_o<<<dim3((BATCH * SEQ) / 128, DIMC / 256), 512, 0, stream>>>(Ob, WoT, bo, (float*)d_out);
}

// Round 4
// 335.129 us; speedup vs baseline: 1.0011x; 1.0011x over previous
//
#include <hip/hip_runtime.h>
#include <cstdint>
#include <math.h>

typedef __bf16 bf16_t;
typedef __bf16 bf16x8 __attribute__((ext_vector_type(8)));
typedef __bf16 bf16x4 __attribute__((ext_vector_type(4)));
typedef float f32x4 __attribute__((ext_vector_type(4)));

#define MFMA16(a, b, c) __builtin_amdgcn_mfma_f32_16x16x32_bf16((a), (b), (c), 0, 0, 0)

static constexpr int BATCH = 4;
static constexpr int SEQ = 2048;
static constexpr int DIMC = 1024;
static constexpr int NH = 16;
static constexpr int HD = 64;

__device__ __forceinline__ void async_copy16(void* lds, const void* g) {
    __builtin_amdgcn_global_load_lds(
        (const __attribute__((address_space(1))) void*)g,
        (__attribute__((address_space(3))) void*)lds, 16, 0, 0);
}

__device__ __forceinline__ float fast_exp2(float x) {
#if __has_builtin(__builtin_amdgcn_exp2f)
    return __builtin_amdgcn_exp2f(x);
#else
    return __expf(x * 0.6931471805599453f);
#endif
}

// ---------------- fp32 -> bf16 elementwise convert, 3 tensors -----------------
__global__ __launch_bounds__(256) void cvt3(const float* __restrict__ q,
                                            const float* __restrict__ k,
                                            const float* __restrict__ v,
                                            bf16_t* __restrict__ out) {
    const float* in = (blockIdx.y == 0) ? q : ((blockIdx.y == 1) ? k : v);
    bf16_t* o = out + (size_t)blockIdx.y * BATCH * SEQ * DIMC;
    const int i = blockIdx.x * 256 + threadIdx.x;  // 8 elems per thread
    const float4 f0 = ((const float4*)in)[i * 2];
    const float4 f1 = ((const float4*)in)[i * 2 + 1];
    bf16x8 vv;
    vv[0] = (bf16_t)f0.x; vv[1] = (bf16_t)f0.y; vv[2] = (bf16_t)f0.z; vv[3] = (bf16_t)f0.w;
    vv[4] = (bf16_t)f1.x; vv[5] = (bf16_t)f1.y; vv[6] = (bf16_t)f1.z; vv[7] = (bf16_t)f1.w;
    ((bf16x8*)o)[i] = vv;
}

// ---------------- weight transpose + fp32->bf16 convert -----------------
__global__ __launch_bounds__(256) void transpose_cvt(const float* __restrict__ W0,
                                                     const float* __restrict__ W1,
                                                     const float* __restrict__ W2,
                                                     const float* __restrict__ W3,
                                                     bf16_t* __restrict__ out) {
    const float* Ws[4] = {W0, W1, W2, W3};
    const float* W = Ws[blockIdx.z];
    bf16_t* Wt = out + (size_t)blockIdx.z * DIMC * DIMC;
    __shared__ float tile[32][33];
    const int tx = threadIdx.x & 31;
    const int ty = threadIdx.x >> 5;
    const int x0 = blockIdx.x * 32;
    const int y0 = blockIdx.y * 32;
    #pragma unroll
    for (int j = ty; j < 32; j += 8)
        tile[j][tx] = W[(size_t)(y0 + j) * DIMC + x0 + tx];
    __syncthreads();
    #pragma unroll
    for (int j = ty; j < 32; j += 8)
        Wt[(size_t)(x0 + j) * DIMC + y0 + tx] = (bf16_t)tile[tx][j];
}

// ---------------- rope tables -----------------
__global__ __launch_bounds__(256) void rope_tab(float* __restrict__ cosT, float* __restrict__ sinT) {
    const int idx = blockIdx.x * 256 + threadIdx.x;  // 65536 = 2048*32
    const int t = idx >> 5;
    const int p = idx & 31;
    const float inv = exp2f(-0.41524101186092029f * (float)p);
    const float ang = (float)t * inv;
    float s, c;
    sincosf(ang, &s, &c);
    cosT[idx] = c;
    sinT[idx] = s;
}

// ===================== 8-phase-style GEMM cores =====================
// BN=256, BK=32, 8 waves (2x4), ring-of-4 LDS K-tile buffers, stages always
// target buf (t+2)%4 (disjoint from read buf t%4 and next buf (t+1)%4 ->
// no write-to-read hazard).  Per phase: {ds_read subtile || stage half-tile}
// -> s_barrier -> lgkmcnt(0) -> sched_barrier(0) -> setprio(1) -> 8 MFMA ->
// setprio(0) -> s_barrier.  ONE counted vmcnt per K-tile (never 0 in steady
// state): at tile t's last phase, vmcnt leaves exactly tile t's own stages
// outstanding => tile t+1's stages (issued during t-1) are landed before the
// barrier that opens tile t+1's reads.
// LDS swizzle: granule g of row r at r*64B + ((g ^ f(r))*16B),
// f(r)=(r&3)^((r>>2)&3); write-side pre-swizzles the global source.

// ---- MI=8 core (BM=256): 4 phases/tile, stage halves A0,A1,B0,B1(t+2) ----
__device__ __forceinline__ void gemm_core8(const bf16_t* __restrict__ A,
                                           const bf16_t* __restrict__ Bt,
                                           const int row0, const int col0,
                                           bf16_t* As, bf16_t* Bs, const int tid,
                                           f32x4 (&acc)[8][4]) {
    constexpr int ABUF = 8192;  // elems per K-tile buffer (256x32)
    constexpr int BBUF = 8192;
    constexpr int NT = DIMC / 32;  // 32
    const int wid = tid >> 6;
    const int lane = tid & 63;
    const int l15 = lane & 15;
    const int quad = lane >> 4;
    const int wr = wid >> 2;  // 0..1
    const int wc = wid & 3;   // 0..3
    const int rIn = lane >> 2;
    const int gW = ((lane & 3) ^ ((rIn & 3) ^ ((rIn >> 2) & 3))) * 8;
    const int fR = (l15 & 3) ^ ((l15 >> 2) & 3);
    const int rdoff = (quad ^ fR) << 3;

#define STG_A8(bi, kt, h)                                                     \
    async_copy16(As + (bi)*ABUF + (h)*4096 + wid * 512,                       \
                 A + (size_t)(row0 + (h)*128 + wid * 16 + rIn) * DIMC +       \
                     (kt)*32 + gW);
#define STG_B8(bi, kt, h)                                                     \
    async_copy16(Bs + (bi)*BBUF + (h)*4096 + wid * 512,                       \
                 Bt + (size_t)(col0 + (h)*128 + wid * 16 + rIn) * DIMC +      \
                     (kt)*32 + gW);

    // prologue: stage tiles 0 and 1 fully; ensure tile 0 landed (vmcnt(4))
    STG_A8(0, 0, 0) STG_A8(0, 0, 1) STG_B8(0, 0, 0) STG_B8(0, 0, 1)
    STG_A8(1, 1, 0) STG_A8(1, 1, 1) STG_B8(1, 1, 0) STG_B8(1, 1, 1)
    asm volatile("s_waitcnt vmcnt(4)" ::: "memory");
    __builtin_amdgcn_s_barrier();

    #pragma unroll 1
    for (int t = 0; t < NT; ++t) {
        const int rb = t & 3;
        const int sb = (t + 2) & 3;
        const int kt2 = t + 2;
        const bool st = kt2 < NT;
        const bf16_t* as = As + rb * ABUF;
        const bf16_t* bs = Bs + rb * BBUF;
        bf16x8 af[4], bf[4];
        // ---- P1: read A(mi0-3) + B(ni0-1); stage A-half0(t+2) ----
        #pragma unroll
        for (int i = 0; i < 4; ++i)
            af[i] = *(const bf16x8*)&as[(wr * 128 + i * 16 + l15) * 32 + rdoff];
        #pragma unroll
        for (int i = 0; i < 2; ++i)
            bf[i] = *(const bf16x8*)&bs[(wc * 64 + i * 16 + l15) * 32 + rdoff];
        if (st) STG_A8(sb, kt2, 0)
        __builtin_amdgcn_s_barrier();
        asm volatile("s_waitcnt lgkmcnt(0)" ::: "memory");
        __builtin_amdgcn_sched_barrier(0);
        __builtin_amdgcn_s_setprio(1);
        #pragma unroll
        for (int mi = 0; mi < 4; ++mi)
            #pragma unroll
            for (int ni = 0; ni < 2; ++ni)
                acc[mi][ni] = MFMA16(af[mi], bf[ni], acc[mi][ni]);
        __builtin_amdgcn_s_setprio(0);
        __builtin_amdgcn_s_barrier();
        // ---- P2: read B(ni2-3); stage A-half1(t+2) ----
        #pragma unroll
        for (int i = 2; i < 4; ++i)
            bf[i] = *(const bf16x8*)&bs[(wc * 64 + i * 16 + l15) * 32 + rdoff];
        if (st) STG_A8(sb, kt2, 1)
        __builtin_amdgcn_s_barrier();
        asm volatile("s_waitcnt lgkmcnt(0)" ::: "memory");
        __builtin_amdgcn_sched_barrier(0);
        __builtin_amdgcn_s_setprio(1);
        #pragma unroll
        for (int mi = 0; mi < 4; ++mi)
            #pragma unroll
            for (int ni = 2; ni < 4; ++ni)
                acc[mi][ni] = MFMA16(af[mi], bf[ni], acc[mi][ni]);
        __builtin_amdgcn_s_setprio(0);
        __builtin_amdgcn_s_barrier();
        // ---- P3: read A(mi4-7) (reuse af); stage B-half0(t+2) ----
        #pragma unroll
        for (int i = 0; i < 4; ++i)
            af[i] = *(const bf16x8*)&as[(wr * 128 + (4 + i) * 16 + l15) * 32 + rdoff];
        if (st) STG_B8(sb, kt2, 0)
        __builtin_amdgcn_s_barrier();
        asm volatile("s_waitcnt lgkmcnt(0)" ::: "memory");
        __builtin_amdgcn_sched_barrier(0);
        __builtin_amdgcn_s_setprio(1);
        #pragma unroll
        for (int mi = 0; mi < 4; ++mi)
            #pragma unroll
            for (int ni = 0; ni < 2; ++ni)
                acc[4 + mi][ni] = MFMA16(af[mi], bf[ni], acc[4 + mi][ni]);
        __builtin_amdgcn_s_setprio(0);
        __builtin_amdgcn_s_barrier();
        // ---- P4: stage B-half1(t+2); MFMA; counted vmcnt; barrier ----
        if (st) STG_B8(sb, kt2, 1)
        __builtin_amdgcn_s_setprio(1);
        #pragma unroll
        for (int mi = 0; mi < 4; ++mi)
            #pragma unroll
            for (int ni = 2; ni < 4; ++ni)
                acc[4 + mi][ni] = MFMA16(af[mi], bf[ni], acc[4 + mi][ni]);
        __builtin_amdgcn_s_setprio(0);
        if (t < NT - 2)
            asm volatile("s_waitcnt vmcnt(4)" ::: "memory");
        else
            asm volatile("s_waitcnt vmcnt(0)" ::: "memory");
        __builtin_amdgcn_s_barrier();
    }
#undef STG_A8
#undef STG_B8
}

// ---- MI=4 core (BM=128): 2 phases/tile, stages A,B0 (P1) and B1 (P2) ----
__device__ __forceinline__ void gemm_core4(const bf16_t* __restrict__ A,
                                           const bf16_t* __restrict__ Bt,
                                           const int row0, const int col0,
                                           bf16_t* As, bf16_t* Bs, const int tid,
                                           f32x4 (&acc)[4][4]) {
    constexpr int ABUF = 4096;  // 128x32
    constexpr int BBUF = 8192;  // 256x32
    constexpr int NT = DIMC / 32;
    const int wid = tid >> 6;
    const int lane = tid & 63;
    const int l15 = lane & 15;
    const int quad = lane >> 4;
    const int wr = wid >> 2;
    const int wc = wid & 3;
    const int rIn = lane >> 2;
    const int gW = ((lane & 3) ^ ((rIn & 3) ^ ((rIn >> 2) & 3))) * 8;
    const int fR = (l15 & 3) ^ ((l15 >> 2) & 3);
    const int rdoff = (quad ^ fR) << 3;

#define STG_A4(bi, kt)                                                        \
    async_copy16(As + (bi)*ABUF + wid * 512,                                  \
                 A + (size_t)(row0 + wid * 16 + rIn) * DIMC + (kt)*32 + gW);
#define STG_B4(bi, kt, h)                                                     \
    async_copy16(Bs + (bi)*BBUF + (h)*4096 + wid * 512,                       \
                 Bt + (size_t)(col0 + (h)*128 + wid * 16 + rIn) * DIMC +      \
                     (kt)*32 + gW);

    STG_A4(0, 0) STG_B4(0, 0, 0) STG_B4(0, 0, 1)
    STG_A4(1, 1) STG_B4(1, 1, 0) STG_B4(1, 1, 1)
    asm volatile("s_waitcnt vmcnt(3)" ::: "memory");
    __builtin_amdgcn_s_barrier();

    #pragma unroll 1
    for (int t = 0; t < NT; ++t) {
        const int rb = t & 3;
        const int sb = (t + 2) & 3;
        const int kt2 = t + 2;
        const bool st = kt2 < NT;
        const bf16_t* as = As + rb * ABUF;
        const bf16_t* bs = Bs + rb * BBUF;
        bf16x8 af[4], bf[4];
        // ---- P1: read A(mi0-3) + B(ni0-1); stage A(t+2), B-half0(t+2) ----
        #pragma unroll
        for (int i = 0; i < 4; ++i)
            af[i] = *(const bf16x8*)&as[(wr * 64 + i * 16 + l15) * 32 + rdoff];
        #pragma unroll
        for (int i = 0; i < 2; ++i)
            bf[i] = *(const bf16x8*)&bs[(wc * 64 + i * 16 + l15) * 32 + rdoff];
        if (st) { STG_A4(sb, kt2) STG_B4(sb, kt2, 0) }
        __builtin_amdgcn_s_barrier();
        asm volatile("s_waitcnt lgkmcnt(0)" ::: "memory");
        __builtin_amdgcn_sched_barrier(0);
        __builtin_amdgcn_s_setprio(1);
        #pragma unroll
        for (int mi = 0; mi < 4; ++mi)
            #pragma unroll
            for (int ni = 0; ni < 2; ++ni)
                acc[mi][ni] = MFMA16(af[mi], bf[ni], acc[mi][ni]);
        __builtin_amdgcn_s_setprio(0);
        __builtin_amdgcn_s_barrier();
        // ---- P2: read B(ni2-3); stage B-half1(t+2); counted vmcnt ----
        #pragma unroll
        for (int i = 2; i < 4; ++i)
            bf[i] = *(const bf16x8*)&bs[(wc * 64 + i * 16 + l15) * 32 + rdoff];
        if (st) STG_B4(sb, kt2, 1)
        __builtin_amdgcn_s_barrier();
        asm volatile("s_waitcnt lgkmcnt(0)" ::: "memory");
        __builtin_amdgcn_sched_barrier(0);
        __builtin_amdgcn_s_setprio(1);
        #pragma unroll
        for (int mi = 0; mi < 4; ++mi)
            #pragma unroll
            for (int ni = 2; ni < 4; ++ni)
                acc[mi][ni] = MFMA16(af[mi], bf[ni], acc[mi][ni]);
        __builtin_amdgcn_s_setprio(0);
        if (t < NT - 2)
            asm volatile("s_waitcnt vmcnt(3)" ::: "memory");
        else
            asm volatile("s_waitcnt vmcnt(0)" ::: "memory");
        __builtin_amdgcn_s_barrier();
    }
#undef STG_A4
#undef STG_B4
}

// ---------------- fused QKV GEMM (256x256 tile, 512 thr) -----------------
// Grid (x=row-panel 32, y=col 4, z=3): dispatch%8 = x%8 -> all col-blocks of a
// row-panel share one XCD (FETCH-minimal, round-3 verified).
// z selects (A, W, bias, out). Q (z==0) pre-scaled by 0.125*log2(e).
__global__ __launch_bounds__(512, 2) void gemm_qkv(const bf16_t* __restrict__ Cb,
                                                   const bf16_t* __restrict__ Wt3,
                                                   const float* __restrict__ bq,
                                                   const float* __restrict__ bk,
                                                   const float* __restrict__ bv,
                                                   bf16_t* __restrict__ Qr,
                                                   bf16_t* __restrict__ Kr,
                                                   bf16_t* __restrict__ Vr,
                                                   const float* __restrict__ cosT,
                                                   const float* __restrict__ sinT) {
    __shared__ __align__(16) unsigned char smem[131072];  // 4x16KB A + 4x16KB B
    bf16_t* As = (bf16_t*)smem;
    bf16_t* Bs = (bf16_t*)(smem + 65536);
    float* eps = (float*)smem;  // epilogue alias: 32 x 264 fp32 = 33.8KB
    const int z = blockIdx.z;
    const bf16_t* A = Cb + (size_t)z * BATCH * SEQ * DIMC;
    const bf16_t* Bt = Wt3 + (size_t)z * DIMC * DIMC;
    const float* bias = (z == 0) ? bq : ((z == 1) ? bk : bv);
    bf16_t* outp = (z == 0) ? Qr : ((z == 1) ? Kr : Vr);
    const bool rope = (z < 2);
    const int tid = threadIdx.x;
    const int row0 = blockIdx.x * 256, col0 = blockIdx.y * 256;
    f32x4 acc[8][4] = {};
    gemm_core8(A, Bt, row0, col0, As, Bs, tid, acc);

    const int wid = tid >> 6;
    const int lane = tid & 63;
    const int l15 = lane & 15;
    const int quad = lane >> 4;
    const int wr = wid >> 2, wc = wid & 3;
    float bvl[4];
    #pragma unroll
    for (int ni = 0; ni < 4; ++ni) bvl[ni] = bias[col0 + wc * 64 + ni * 16 + l15];
    // read-phase mapping: 512 threads = 32 rows x 16 col-groups of 16
    const int lr = tid >> 4;
    const int cg = tid & 15;
    const int c0 = cg * 16;
    const int h = (col0 + c0) >> 6;
    const int dbase = c0 & 63;
    const float osc = (z == 0) ? 0.18033688011112043f : 1.0f;
    #pragma unroll
    for (int p = 0; p < 8; ++p) {  // p = mi slab: rows {wr*128 + p*16 + 0..15}
        __syncthreads();
        #pragma unroll
        for (int ni = 0; ni < 4; ++ni)
            #pragma unroll
            for (int r = 0; r < 4; ++r)
                eps[(wr * 16 + quad * 4 + r) * 264 + wc * 64 + ni * 16 + l15] =
                    acc[p][ni][r] + bvl[ni];
        __syncthreads();
        const int grow = row0 + (lr >> 4) * 128 + p * 16 + (lr & 15);
        const int tq = grow & (SEQ - 1);
        const int bb = grow >> 11;
        float vals[16];
        #pragma unroll
        for (int q4 = 0; q4 < 4; ++q4) {
            f32x4 vv = *(const f32x4*)&eps[lr * 264 + c0 + q4 * 4];
            vals[q4 * 4 + 0] = vv[0]; vals[q4 * 4 + 1] = vv[1];
            vals[q4 * 4 + 2] = vv[2]; vals[q4 * 4 + 3] = vv[3];
        }
        bf16x8 o0, o1;
        if (rope) {
            const int pbase = tq * 32 + (dbase >> 1);
            const float4 cs0 = *(const float4*)&cosT[pbase];
            const float4 cs1 = *(const float4*)&cosT[pbase + 4];
            const float4 sn0 = *(const float4*)&sinT[pbase];
            const float4 sn1 = *(const float4*)&sinT[pbase + 4];
            const float cc[8] = {cs0.x, cs0.y, cs0.z, cs0.w, cs1.x, cs1.y, cs1.z, cs1.w};
            const float ss[8] = {sn0.x, sn0.y, sn0.z, sn0.w, sn1.x, sn1.y, sn1.z, sn1.w};
            #pragma unroll
            for (int i = 0; i < 8; ++i) {
                const float e = vals[2 * i], o = vals[2 * i + 1];
                const float oe = (e * cc[i] - o * ss[i]) * osc;
                const float oo = (e * ss[i] + o * cc[i]) * osc;
                if (i < 4) { o0[2 * i] = (bf16_t)oe; o0[2 * i + 1] = (bf16_t)oo; }
                else { o1[2 * (i - 4)] = (bf16_t)oe; o1[2 * (i - 4) + 1] = (bf16_t)oo; }
            }
        } else {
            #pragma unroll
            for (int i = 0; i < 8; ++i) o0[i] = (bf16_t)vals[i];
            #pragma unroll
            for (int i = 0; i < 8; ++i) o1[i] = (bf16_t)vals[8 + i];
        }
        bf16_t* dst = outp + (((size_t)bb * NH + h) * SEQ + tq) * HD + dbase;
        *(bf16x8*)dst = o0;
        *(bf16x8*)(dst + 8) = o1;
    }
}

// ---------------- output GEMM (128x256 tile, fp32 out) -----------------
// Grid (x=row-panel 64, y=col 4): 256 blocks = exactly 1/CU.
__global__ __launch_bounds__(512, 2) void gemm_o(const bf16_t* __restrict__ A,
                                                 const bf16_t* __restrict__ Bt,
                                                 const float* __restrict__ bias,
                                                 float* __restrict__ out) {
    __shared__ __align__(16) unsigned char smem[98304];  // 4x8KB A + 4x16KB B
    bf16_t* As = (bf16_t*)smem;
    bf16_t* Bs = (bf16_t*)(smem + 32768);
    const int tid = threadIdx.x;
    const int row0 = blockIdx.x * 128, col0 = blockIdx.y * 256;
    f32x4 acc[4][4] = {};
    gemm_core4(A, Bt, row0, col0, As, Bs, tid, acc);
    const int wid = tid >> 6;
    const int lane = tid & 63;
    const int l15 = lane & 15;
    const int quad = lane >> 4;
    const int wr = wid >> 2, wc = wid & 3;
    #pragma unroll
    for (int ni = 0; ni < 4; ++ni) {
        const int col = col0 + wc * 64 + ni * 16 + l15;
        const float bvl = bias[col];
        #pragma unroll
        for (int mi = 0; mi < 4; ++mi) {
            #pragma unroll
            for (int r = 0; r < 4; ++r) {
                const int row = row0 + wr * 64 + mi * 16 + quad * 4 + r;
                out[(size_t)row * DIMC + col] = acc[mi][ni][r] + bvl;
            }
        }
    }
}

// ---------------- flash attention (causal, no-max softmax, S^T trick) -----------------
// Qr/Kr/Vr: bf16 [B,H,S,64] (rope on Q,K; Q pre-scaled by 0.125*log2e). O: bf16 [B*S,1024]
// Single-barrier software pipeline, Ks/Vt double-buffered.
__global__ __launch_bounds__(256) void attn_kernel(const bf16_t* __restrict__ Qr,
                                                   const bf16_t* __restrict__ Kr,
                                                   const bf16_t* __restrict__ Vr,
                                                   bf16_t* __restrict__ O) {
    __shared__ bf16_t Ks[2][64 * 64];   // swizzled [s][d], double-buffered (16 KB)
    __shared__ bf16_t Vt[2][64 * 72];   // [d][s] stride 72, double-buffered (18 KB)
    __shared__ bf16_t Ps[4][32 * 72];   // per-wave [t-local][s], stride 72 (18 KB)
    const int tid = threadIdx.x;
    const int w = tid >> 6;
    const int lane = tid & 63;
    const int l15 = lane & 15;
    const int quad = lane >> 4;
    const int bh = blockIdx.x;
    const int b = bh >> 4, h = bh & 15;
    const bf16_t* Qb = Qr + (size_t)bh * SEQ * HD;
    const bf16_t* Kb = Kr + (size_t)bh * SEQ * HD;
    const bf16_t* Vb = Vr + (size_t)bh * SEQ * HD;

    bf16x8 ones;
    #pragma unroll
    for (int j8 = 0; j8 < 8; ++j8) ones[j8] = (bf16_t)1.0f;
    bf16x8 idB[2];
    #pragma unroll
    for (int ch = 0; ch < 2; ++ch)
        #pragma unroll
        for (int j8 = 0; j8 < 8; ++j8)
            idB[ch][j8] = (quad * 8 + j8 == ch * 16 + l15) ? (bf16_t)1.0f : (bf16_t)0.0f;

    const int sIn = lane >> 3;              // s within chunk
    const int gK = ((lane & 7) ^ sIn) * 8;  // swizzled source d-offset
    const int fK = (l15 & 7);               // read-side swizzle key

#define VTRANS(buf, a0, a1)                                                      \
    {                                                                            \
        _Pragma("unroll") for (int c = 0; c < 4; ++c) {                          \
            f32x4 zt = {};                                                       \
            f32x4 tv = MFMA16((c < 2) ? (a0) : (a1), idB[c & 1], zt);            \
            bf16x4 pkt;                                                          \
            _Pragma("unroll") for (int rr = 0; rr < 4; ++rr)                     \
                pkt[rr] = (bf16_t)tv[rr];                                        \
            *(bf16x4*)&Vt[buf][(c * 16 + l15) * 72 + w * 16 + quad * 4] = pkt;   \
        }                                                                        \
    }

    const int j = 15 - (int)blockIdx.y;  // big tiles first (LPT)
    const int q0 = j * 128;
    bf16x8 qa[2][2];
    #pragma unroll
    for (int mg = 0; mg < 2; ++mg)
        #pragma unroll
        for (int kc = 0; kc < 2; ++kc)
            qa[mg][kc] = *(const bf16x8*)(Qb + (size_t)(q0 + mg * 64 + w * 16 + l15) * HD +
                                          kc * 32 + quad * 8);
    f32x4 acco[2][4] = {};
    f32x4 accl[2] = {};
    const int nIter = 2 * j + 2;

    #pragma unroll
    for (int ci = 0; ci < 2; ++ci) {
        const int c = 2 * w + ci;
        async_copy16(&Ks[0][c * 512], Kb + (size_t)(c * 8 + sIn) * HD + gK);
    }
    {
        const bf16_t* vsrc = Vb + (size_t)(w * 16 + l15) * HD + quad * 8;
        bf16x8 pv0 = *(const bf16x8*)vsrc;
        bf16x8 pv1 = *(const bf16x8*)(vsrc + 32);
        VTRANS(0, pv0, pv1);
    }
    __syncthreads();

    int cur = 0;
    for (int it = 0; it < nIter; ++it) {
        const int nxt = cur ^ 1;
        const bool hn = (it + 1 < nIter);
        bf16x8 av0, av1;
        if (hn) {
            const int s1 = (it + 1) * 64;
            #pragma unroll
            for (int ci = 0; ci < 2; ++ci) {
                const int c = 2 * w + ci;
                async_copy16(&Ks[nxt][c * 512], Kb + (size_t)(s1 + c * 8 + sIn) * HD + gK);
            }
            const bf16_t* vsrc = Vb + (size_t)(s1 + w * 16 + l15) * HD + quad * 8;
            av0 = *(const bf16x8*)vsrc;
            av1 = *(const bf16x8*)(vsrc + 32);
        }
        bf16x8 kb[4][2];
        #pragma unroll
        for (int mt = 0; mt < 4; ++mt)
            #pragma unroll
            for (int kc = 0; kc < 2; ++kc)
                kb[mt][kc] = *(const bf16x8*)&Ks[cur][(mt * 16 + l15) * 64 +
                                                      (((kc * 4 + quad) ^ fK) << 3)];
        const bool skip0 = (it == 2 * j + 1);
        f32x4 zz[2][4];
        __builtin_amdgcn_s_setprio(1);
        #pragma unroll
        for (int mg = 0; mg < 2; ++mg) {
            if (mg == 0 && skip0) continue;
            #pragma unroll
            for (int mt = 0; mt < 4; ++mt) {
                f32x4 z = {};
                z = MFMA16(kb[mt][0], qa[mg][0], z);
                z = MFMA16(kb[mt][1], qa[mg][1], z);
                zz[mg][mt] = z;
            }
        }
        __builtin_amdgcn_s_setprio(0);
        #pragma unroll
        for (int mg = 0; mg < 2; ++mg) {
            if (mg == 0 && skip0) continue;
            const bool diag = (it == 2 * j + mg);
            #pragma unroll
            for (int mt = 0; mt < 4; ++mt) {
                bf16x4 pk;
                #pragma unroll
                for (int r = 0; r < 4; ++r) {
                    float v = zz[mg][mt][r];
                    if (diag && (mt * 16 + quad * 4 + r > w * 16 + l15)) v = -INFINITY;
                    pk[r] = (bf16_t)fast_exp2(v);
                }
                *(bf16x4*)&Ps[w][(mg * 16 + l15) * 72 + mt * 16 + quad * 4] = pk;
            }
        }
        asm volatile("s_waitcnt lgkmcnt(0)" ::: "memory");
        bf16x8 vb[4][2];
        #pragma unroll
        for (int dt = 0; dt < 4; ++dt)
            #pragma unroll
            for (int kc = 0; kc < 2; ++kc)
                vb[dt][kc] = *(const bf16x8*)&Vt[cur][(dt * 16 + l15) * 72 + kc * 32 + quad * 8];
        #pragma unroll
        for (int mg = 0; mg < 2; ++mg) {
            if (mg == 0 && skip0) continue;
            const bf16x8 pa0 = *(const bf16x8*)&Ps[w][(mg * 16 + l15) * 72 + quad * 8];
            const bf16x8 pa1 = *(const bf16x8*)&Ps[w][(mg * 16 + l15) * 72 + 32 + quad * 8];
            __builtin_amdgcn_s_setprio(1);
            #pragma unroll
            for (int dt = 0; dt < 4; ++dt) {
                acco[mg][dt] = MFMA16(pa0, vb[dt][0], acco[mg][dt]);
                acco[mg][dt] = MFMA16(pa1, vb[dt][1], acco[mg][dt]);
            }
            accl[mg] = MFMA16(pa0, ones, accl[mg]);
            accl[mg] = MFMA16(pa1, ones, accl[mg]);
            __builtin_amdgcn_s_setprio(0);
        }
        if (hn) VTRANS(nxt, av0, av1);
        __syncthreads();
        cur = nxt;
    }
    #pragma unroll
    for (int mg = 0; mg < 2; ++mg) {
        #pragma unroll
        for (int r = 0; r < 4; ++r) {
            const float inv = 1.0f / accl[mg][r];
            const int trow = q0 + mg * 64 + w * 16 + quad * 4 + r;
            bf16_t* orow = O + ((size_t)(b * SEQ + trow)) * DIMC + h * HD;
            #pragma unroll
            for (int dt = 0; dt < 4; ++dt)
                orow[dt * 16 + l15] = (bf16_t)(acco[mg][dt][r] * inv);
        }
    }
#undef VTRANS
}

extern "C" void kernel_launch(void* const* d_in, const int* in_sizes, int n_in,
                              void* d_out, int out_size, void* d_ws, size_t ws_size,
                              hipStream_t stream) {
    const float* query = (const float*)d_in[0];
    const float* key = (const float*)d_in[1];
    const float* value = (const float*)d_in[2];
    const float* Wq = (const float*)d_in[3];
    const float* bq = (const float*)d_in[4];
    const float* Wk = (const float*)d_in[5];
    const float* bk = (const float*)d_in[6];
    const float* Wv = (const float*)d_in[7];
    const float* bv = (const float*)d_in[8];
    const float* Wo = (const float*)d_in[9];
    const float* bo = (const float*)d_in[10];

    char* ws = (char*)d_ws;
    const size_t WT_BYTES = (size_t)DIMC * DIMC * sizeof(bf16_t);          // 2 MB
    const size_t ACT_BYTES = (size_t)BATCH * SEQ * DIMC * sizeof(bf16_t);  // 16 MB
    bf16_t* WT = (bf16_t*)ws;  // WqT,WkT,WvT,WoT consecutive (8 MB)
    bf16_t* WoT = WT + 3 * (size_t)DIMC * DIMC;
    float* cosT = (float*)(ws + 4 * WT_BYTES);
    float* sinT = (float*)(ws + 4 * WT_BYTES + 262144);
    bf16_t* Cb = (bf16_t*)(ws + 4 * WT_BYTES + 2 * 262144);  // 3x16 MB bf16 inputs
    bf16_t* Qr = (bf16_t*)((char*)Cb + 3 * ACT_BYTES);
    bf16_t* Kr = (bf16_t*)((char*)Cb + 4 * ACT_BYTES);
    bf16_t* Vr = (bf16_t*)((char*)Cb + 5 * ACT_BYTES);
    bf16_t* Ob = Cb;  // attention output aliases Cq (free after QKV GEMMs)

    transpose_cvt<<<dim3(32, 32, 4), 256, 0, stream>>>(Wq, Wk, Wv, Wo, WT);
    rope_tab<<<dim3(256), 256, 0, stream>>>(cosT, sinT);
    cvt3<<<dim3(4096, 3), 256, 0, stream>>>(query, key, value, Cb);
    gemm_qkv<<<dim3((BATCH * SEQ) / 256, DIMC / 256, 3), 512, 0, stream>>>(
        Cb, WT, bq, bk, bv, Qr, Kr, Vr, cosT, sinT);
    attn_kernel<<<dim3(BATCH * NH, 16), 256, 0, stream>>>(Qr, Kr, Vr, Ob);
    gemm_o<<<dim3((BATCH * SEQ) / 128, DIMC / 256), 512, 0, stream>>>(Ob, WoT, bo, (float*)d_out);
}

// Round 5
// 318.570 us; speedup vs baseline: 1.0532x; 1.0520x over previous
//
#include <hip/hip_runtime.h>
#include <cstdint>
#include <math.h>

typedef __bf16 bf16_t;
typedef __bf16 bf16x8 __attribute__((ext_vector_type(8)));
typedef __bf16 bf16x4 __attribute__((ext_vector_type(4)));
typedef float f32x4 __attribute__((ext_vector_type(4)));

#define MFMA16(a, b, c) __builtin_amdgcn_mfma_f32_16x16x32_bf16((a), (b), (c), 0, 0, 0)

static constexpr int BATCH = 4;
static constexpr int SEQ = 2048;
static constexpr int DIMC = 1024;
static constexpr int NH = 16;
static constexpr int HD = 64;

__device__ __forceinline__ void async_copy16(void* lds, const void* g) {
    __builtin_amdgcn_global_load_lds(
        (const __attribute__((address_space(1))) void*)g,
        (__attribute__((address_space(3))) void*)lds, 16, 0, 0);
}

__device__ __forceinline__ float fast_exp2(float x) {
#if __has_builtin(__builtin_amdgcn_exp2f)
    return __builtin_amdgcn_exp2f(x);
#else
    return __expf(x * 0.6931471805599453f);
#endif
}

// ---------------- fp32 -> bf16 elementwise convert, 3 tensors -----------------
__global__ __launch_bounds__(256) void cvt3(const float* __restrict__ q,
                                            const float* __restrict__ k,
                                            const float* __restrict__ v,
                                            bf16_t* __restrict__ out) {
    const float* in = (blockIdx.y == 0) ? q : ((blockIdx.y == 1) ? k : v);
    bf16_t* o = out + (size_t)blockIdx.y * BATCH * SEQ * DIMC;
    const int i = blockIdx.x * 256 + threadIdx.x;  // 8 elems per thread
    const float4 f0 = ((const float4*)in)[i * 2];
    const float4 f1 = ((const float4*)in)[i * 2 + 1];
    bf16x8 vv;
    vv[0] = (bf16_t)f0.x; vv[1] = (bf16_t)f0.y; vv[2] = (bf16_t)f0.z; vv[3] = (bf16_t)f0.w;
    vv[4] = (bf16_t)f1.x; vv[5] = (bf16_t)f1.y; vv[6] = (bf16_t)f1.z; vv[7] = (bf16_t)f1.w;
    ((bf16x8*)o)[i] = vv;
}

// ---------------- weight transpose + fp32->bf16 convert -----------------
__global__ __launch_bounds__(256) void transpose_cvt(const float* __restrict__ W0,
                                                     const float* __restrict__ W1,
                                                     const float* __restrict__ W2,
                                                     const float* __restrict__ W3,
                                                     bf16_t* __restrict__ out) {
    const float* Ws[4] = {W0, W1, W2, W3};
    const float* W = Ws[blockIdx.z];
    bf16_t* Wt = out + (size_t)blockIdx.z * DIMC * DIMC;
    __shared__ float tile[32][33];
    const int tx = threadIdx.x & 31;
    const int ty = threadIdx.x >> 5;
    const int x0 = blockIdx.x * 32;
    const int y0 = blockIdx.y * 32;
    #pragma unroll
    for (int j = ty; j < 32; j += 8)
        tile[j][tx] = W[(size_t)(y0 + j) * DIMC + x0 + tx];
    __syncthreads();
    #pragma unroll
    for (int j = ty; j < 32; j += 8)
        Wt[(size_t)(x0 + j) * DIMC + y0 + tx] = (bf16_t)tile[tx][j];
}

// ---------------- rope tables -----------------
__global__ __launch_bounds__(256) void rope_tab(float* __restrict__ cosT, float* __restrict__ sinT) {
    const int idx = blockIdx.x * 256 + threadIdx.x;  // 65536 = 2048*32
    const int t = idx >> 5;
    const int p = idx & 31;
    const float inv = exp2f(-0.41524101186092029f * (float)p);
    const float ang = (float)t * inv;
    float s, c;
    sincosf(ang, &s, &c);
    cosT[idx] = c;
    sinT[idx] = s;
}

// ===================== BK=64 GEMM core (BM=128, BN=256) =====================
// 8 waves (2x4), per-wave output 64x64 (mi=4, ni=4, 16x16x32 MFMA, kc=0,1).
// LDS: ring of 3 K-tile buffers, A 16KB + B 32KB each => 144 KB total.
// Row layout: 64 bf16 = 128 B per row (one full bank span). Swizzle: the
// 16B granule g of row r sits at physical granule g ^ (r&7)  (m214's +89%
// conflict fix, adapted to 128B rows). global_load_lds writes LINEARLY;
// the SOURCE granule is pre-swizzled (gl = g ^ (r&7)) and the read applies
// the same involution => both-sides-consistent (rule #21).
//   A wave's ds_read_b128 (fixed kc): lane(quad,l15) hits phys granule
//   (kc*4+quad) ^ (l15&7): any 16-lane group covers all 8 slots 2-way => free.
// Pipeline: stage tile t+2 into buf (t+2)%3 = (t-1)%3 (read-drained: lgkm0
// precedes t-1's last MFMAs which precede t-1's final barrier). Counted
// vmcnt(6) at end of tile t drains exactly tile t+1's 6 loads (t's own 6 for
// t+2 remain in flight); barrier publishes across waves. Never vmcnt(0) in
// steady state (T4). 2 phases/tile (kc=0,1), 16 MFMA each, 2 barriers/phase.
__device__ __forceinline__ void gemm_core64(const bf16_t* __restrict__ A,
                                            const bf16_t* __restrict__ Bt,
                                            const int row0, const int col0,
                                            bf16_t* As, bf16_t* Bs, const int tid,
                                            f32x4 (&acc)[4][4]) {
    constexpr int NT = DIMC / 64;  // 16
    const int wid = tid >> 6;
    const int lane = tid & 63;
    const int l15 = lane & 15;
    const int quad = lane >> 4;
    const int wr = wid >> 2;  // 0..1
    const int wc = wid & 3;   // 0..3
    // staging constants: thread stages chunk (row rL + p*64, phys granule tid&7)
    const int rL = tid >> 3;                          // 0..63
    const int gswE = ((tid & 7) ^ (rL & 7)) * 8;      // source granule (elems)
    // read-side physical granule offsets (elems) for kc=0,1
    const int e0 = ((quad) ^ (l15 & 7)) * 8;
    const int e1 = ((4 + quad) ^ (l15 & 7)) * 8;
    const int aRow = wr * 64 + l15;
    const int bRow = wc * 64 + l15;

#define STG_A64(bi, kt, p)                                                     \
    async_copy16(As + (bi)*8192 + (p)*4096 + tid * 8,                          \
                 A + (size_t)(row0 + (p)*64 + rL) * DIMC + (kt)*64 + gswE);
#define STG_B64(bi, kt, p)                                                     \
    async_copy16(Bs + (bi)*16384 + (p)*4096 + tid * 8,                         \
                 Bt + (size_t)(col0 + (p)*64 + rL) * DIMC + (kt)*64 + gswE);

    // prologue: stage tiles 0 and 1 (6 loads/thread each)
    STG_A64(0, 0, 0) STG_A64(0, 0, 1)
    STG_B64(0, 0, 0) STG_B64(0, 0, 1) STG_B64(0, 0, 2) STG_B64(0, 0, 3)
    STG_A64(1, 1, 0) STG_A64(1, 1, 1)
    STG_B64(1, 1, 0) STG_B64(1, 1, 1) STG_B64(1, 1, 2) STG_B64(1, 1, 3)
    asm volatile("s_waitcnt vmcnt(6)" ::: "memory");  // tile 0 landed
    __builtin_amdgcn_s_barrier();

    int rb = 0;
    #pragma unroll 1
    for (int t = 0; t < NT; ++t) {
        int sb = rb + 2;
        if (sb >= 3) sb -= 3;
        const int kt2 = t + 2;
        const bool st = kt2 < NT;
        const bf16_t* as = As + rb * 8192;
        const bf16_t* bs = Bs + rb * 16384;
        bf16x8 af[4], bf[4];
        // ---- P1 (kc=0): 8 ds_reads; stage A0,A1,B0 of t+2 ----
        #pragma unroll
        for (int mi = 0; mi < 4; ++mi)
            af[mi] = *(const bf16x8*)&as[(aRow + mi * 16) * 64 + e0];
        #pragma unroll
        for (int ni = 0; ni < 4; ++ni)
            bf[ni] = *(const bf16x8*)&bs[(bRow + ni * 16) * 64 + e0];
        if (st) { STG_A64(sb, kt2, 0) STG_A64(sb, kt2, 1) STG_B64(sb, kt2, 0) }
        __builtin_amdgcn_s_barrier();
        asm volatile("s_waitcnt lgkmcnt(0)" ::: "memory");
        __builtin_amdgcn_sched_barrier(0);
        __builtin_amdgcn_s_setprio(1);
        #pragma unroll
        for (int mi = 0; mi < 4; ++mi)
            #pragma unroll
            for (int ni = 0; ni < 4; ++ni)
                acc[mi][ni] = MFMA16(af[mi], bf[ni], acc[mi][ni]);
        __builtin_amdgcn_s_setprio(0);
        __builtin_amdgcn_s_barrier();
        // ---- P2 (kc=1): 8 ds_reads; stage B1,B2,B3 of t+2; counted vmcnt ----
        #pragma unroll
        for (int mi = 0; mi < 4; ++mi)
            af[mi] = *(const bf16x8*)&as[(aRow + mi * 16) * 64 + e1];
        #pragma unroll
        for (int ni = 0; ni < 4; ++ni)
            bf[ni] = *(const bf16x8*)&bs[(bRow + ni * 16) * 64 + e1];
        if (st) { STG_B64(sb, kt2, 1) STG_B64(sb, kt2, 2) STG_B64(sb, kt2, 3) }
        __builtin_amdgcn_s_barrier();
        asm volatile("s_waitcnt lgkmcnt(0)" ::: "memory");
        __builtin_amdgcn_sched_barrier(0);
        __builtin_amdgcn_s_setprio(1);
        #pragma unroll
        for (int mi = 0; mi < 4; ++mi)
            #pragma unroll
            for (int ni = 0; ni < 4; ++ni)
                acc[mi][ni] = MFMA16(af[mi], bf[ni], acc[mi][ni]);
        __builtin_amdgcn_s_setprio(0);
        if (t < NT - 2)
            asm volatile("s_waitcnt vmcnt(6)" ::: "memory");
        else
            asm volatile("s_waitcnt vmcnt(0)" ::: "memory");
        __builtin_amdgcn_s_barrier();
        rb = rb + 1;
        if (rb >= 3) rb = 0;
    }
#undef STG_A64
#undef STG_B64
}

// ---------------- fused QKV GEMM (128x256 tile, 512 thr) -----------------
// Grid (x=row-panel 64, y=col 4, z=3): dispatch%8 = x%8 -> all col-blocks of a
// row-panel share one XCD (FETCH-minimal). 768 blocks = exactly 3 CU-rounds.
// z selects (A, W, bias, out). Q (z==0) pre-scaled by 0.125*log2(e).
__global__ __launch_bounds__(512, 2) void gemm_qkv(const bf16_t* __restrict__ Cb,
                                                   const bf16_t* __restrict__ Wt3,
                                                   const float* __restrict__ bq,
                                                   const float* __restrict__ bk,
                                                   const float* __restrict__ bv,
                                                   bf16_t* __restrict__ Qr,
                                                   bf16_t* __restrict__ Kr,
                                                   bf16_t* __restrict__ Vr,
                                                   const float* __restrict__ cosT,
                                                   const float* __restrict__ sinT) {
    __shared__ __align__(16) unsigned char smem[147456];  // 3x(16KB A + 32KB B)
    bf16_t* As = (bf16_t*)smem;
    bf16_t* Bs = (bf16_t*)(smem + 49152);
    float* eps = (float*)smem;  // epilogue alias: 32 x 264 fp32 = 33.8KB
    const int z = blockIdx.z;
    const bf16_t* A = Cb + (size_t)z * BATCH * SEQ * DIMC;
    const bf16_t* Bt = Wt3 + (size_t)z * DIMC * DIMC;
    const float* bias = (z == 0) ? bq : ((z == 1) ? bk : bv);
    bf16_t* outp = (z == 0) ? Qr : ((z == 1) ? Kr : Vr);
    const bool rope = (z < 2);
    const int tid = threadIdx.x;
    const int row0 = blockIdx.x * 128, col0 = blockIdx.y * 256;
    f32x4 acc[4][4] = {};
    gemm_core64(A, Bt, row0, col0, As, Bs, tid, acc);

    const int wid = tid >> 6;
    const int lane = tid & 63;
    const int l15 = lane & 15;
    const int quad = lane >> 4;
    const int wr = wid >> 2, wc = wid & 3;
    float bvl[4];
    #pragma unroll
    for (int ni = 0; ni < 4; ++ni) bvl[ni] = bias[col0 + wc * 64 + ni * 16 + l15];
    // read-phase mapping: 512 threads = 32 rows x 16 col-groups of 16
    const int lr = tid >> 4;
    const int cg = tid & 15;
    const int c0 = cg * 16;
    const int h = (col0 + c0) >> 6;
    const int dbase = c0 & 63;
    const float osc = (z == 0) ? 0.18033688011112043f : 1.0f;
    #pragma unroll
    for (int p = 0; p < 4; ++p) {  // p = mi slab: rows {row0 + wr*64 + p*16 + ..}
        __syncthreads();
        #pragma unroll
        for (int ni = 0; ni < 4; ++ni)
            #pragma unroll
            for (int r = 0; r < 4; ++r)
                eps[(wr * 16 + quad * 4 + r) * 264 + wc * 64 + ni * 16 + l15] =
                    acc[p][ni][r] + bvl[ni];
        __syncthreads();
        const int grow = row0 + (lr >> 4) * 64 + p * 16 + (lr & 15);
        const int tq = grow & (SEQ - 1);
        const int bb = grow >> 11;
        float vals[16];
        #pragma unroll
        for (int q4 = 0; q4 < 4; ++q4) {
            f32x4 vv = *(const f32x4*)&eps[lr * 264 + c0 + q4 * 4];
            vals[q4 * 4 + 0] = vv[0]; vals[q4 * 4 + 1] = vv[1];
            vals[q4 * 4 + 2] = vv[2]; vals[q4 * 4 + 3] = vv[3];
        }
        bf16x8 o0, o1;
        if (rope) {
            const int pbase = tq * 32 + (dbase >> 1);
            const float4 cs0 = *(const float4*)&cosT[pbase];
            const float4 cs1 = *(const float4*)&cosT[pbase + 4];
            const float4 sn0 = *(const float4*)&sinT[pbase];
            const float4 sn1 = *(const float4*)&sinT[pbase + 4];
            const float cc[8] = {cs0.x, cs0.y, cs0.z, cs0.w, cs1.x, cs1.y, cs1.z, cs1.w};
            const float ss[8] = {sn0.x, sn0.y, sn0.z, sn0.w, sn1.x, sn1.y, sn1.z, sn1.w};
            #pragma unroll
            for (int i = 0; i < 8; ++i) {
                const float e = vals[2 * i], o = vals[2 * i + 1];
                const float oe = (e * cc[i] - o * ss[i]) * osc;
                const float oo = (e * ss[i] + o * cc[i]) * osc;
                if (i < 4) { o0[2 * i] = (bf16_t)oe; o0[2 * i + 1] = (bf16_t)oo; }
                else { o1[2 * (i - 4)] = (bf16_t)oe; o1[2 * (i - 4) + 1] = (bf16_t)oo; }
            }
        } else {
            #pragma unroll
            for (int i = 0; i < 8; ++i) o0[i] = (bf16_t)vals[i];
            #pragma unroll
            for (int i = 0; i < 8; ++i) o1[i] = (bf16_t)vals[8 + i];
        }
        bf16_t* dst = outp + (((size_t)bb * NH + h) * SEQ + tq) * HD + dbase;
        *(bf16x8*)dst = o0;
        *(bf16x8*)(dst + 8) = o1;
    }
}

// ---------------- output GEMM (128x256 tile, fp32 out) -----------------
// Grid (x=row-panel 64, y=col 4): 256 blocks = exactly 1/CU.
__global__ __launch_bounds__(512, 2) void gemm_o(const bf16_t* __restrict__ A,
                                                 const bf16_t* __restrict__ Bt,
                                                 const float* __restrict__ bias,
                                                 float* __restrict__ out) {
    __shared__ __align__(16) unsigned char smem[147456];  // 3x(16KB A + 32KB B)
    bf16_t* As = (bf16_t*)smem;
    bf16_t* Bs = (bf16_t*)(smem + 49152);
    const int tid = threadIdx.x;
    const int row0 = blockIdx.x * 128, col0 = blockIdx.y * 256;
    f32x4 acc[4][4] = {};
    gemm_core64(A, Bt, row0, col0, As, Bs, tid, acc);
    const int wid = tid >> 6;
    const int lane = tid & 63;
    const int l15 = lane & 15;
    const int quad = lane >> 4;
    const int wr = wid >> 2, wc = wid & 3;
    #pragma unroll
    for (int ni = 0; ni < 4; ++ni) {
        const int col = col0 + wc * 64 + ni * 16 + l15;
        const float bvl = bias[col];
        #pragma unroll
        for (int mi = 0; mi < 4; ++mi) {
            #pragma unroll
            for (int r = 0; r < 4; ++r) {
                const int row = row0 + wr * 64 + mi * 16 + quad * 4 + r;
                out[(size_t)row * DIMC + col] = acc[mi][ni][r] + bvl;
            }
        }
    }
}

// ---------------- flash attention (causal, no-max softmax, S^T trick) -----------------
// Qr/Kr/Vr: bf16 [B,H,S,64] (rope on Q,K; Q pre-scaled by 0.125*log2e). O: bf16 [B*S,1024]
// Single-barrier software pipeline, Ks/Vt double-buffered.
__global__ __launch_bounds__(256) void attn_kernel(const bf16_t* __restrict__ Qr,
                                                   const bf16_t* __restrict__ Kr,
                                                   const bf16_t* __restrict__ Vr,
                                                   bf16_t* __restrict__ O) {
    __shared__ bf16_t Ks[2][64 * 64];   // swizzled [s][d], double-buffered (16 KB)
    __shared__ bf16_t Vt[2][64 * 72];   // [d][s] stride 72, double-buffered (18 KB)
    __shared__ bf16_t Ps[4][32 * 72];   // per-wave [t-local][s], stride 72 (18 KB)
    const int tid = threadIdx.x;
    const int w = tid >> 6;
    const int lane = tid & 63;
    const int l15 = lane & 15;
    const int quad = lane >> 4;
    const int bh = blockIdx.x;
    const int b = bh >> 4, h = bh & 15;
    const bf16_t* Qb = Qr + (size_t)bh * SEQ * HD;
    const bf16_t* Kb = Kr + (size_t)bh * SEQ * HD;
    const bf16_t* Vb = Vr + (size_t)bh * SEQ * HD;

    bf16x8 ones;
    #pragma unroll
    for (int j8 = 0; j8 < 8; ++j8) ones[j8] = (bf16_t)1.0f;
    bf16x8 idB[2];
    #pragma unroll
    for (int ch = 0; ch < 2; ++ch)
        #pragma unroll
        for (int j8 = 0; j8 < 8; ++j8)
            idB[ch][j8] = (quad * 8 + j8 == ch * 16 + l15) ? (bf16_t)1.0f : (bf16_t)0.0f;

    const int sIn = lane >> 3;              // s within chunk
    const int gK = ((lane & 7) ^ sIn) * 8;  // swizzled source d-offset
    const int fK = (l15 & 7);               // read-side swizzle key

#define VTRANS(buf, a0, a1)                                                      \
    {                                                                            \
        _Pragma("unroll") for (int c = 0; c < 4; ++c) {                          \
            f32x4 zt = {};                                                       \
            f32x4 tv = MFMA16((c < 2) ? (a0) : (a1), idB[c & 1], zt);            \
            bf16x4 pkt;                                                          \
            _Pragma("unroll") for (int rr = 0; rr < 4; ++rr)                     \
                pkt[rr] = (bf16_t)tv[rr];                                        \
            *(bf16x4*)&Vt[buf][(c * 16 + l15) * 72 + w * 16 + quad * 4] = pkt;   \
        }                                                                        \
    }

    const int j = 15 - (int)blockIdx.y;  // big tiles first (LPT)
    const int q0 = j * 128;
    bf16x8 qa[2][2];
    #pragma unroll
    for (int mg = 0; mg < 2; ++mg)
        #pragma unroll
        for (int kc = 0; kc < 2; ++kc)
            qa[mg][kc] = *(const bf16x8*)(Qb + (size_t)(q0 + mg * 64 + w * 16 + l15) * HD +
                                          kc * 32 + quad * 8);
    f32x4 acco[2][4] = {};
    f32x4 accl[2] = {};
    const int nIter = 2 * j + 2;

    #pragma unroll
    for (int ci = 0; ci < 2; ++ci) {
        const int c = 2 * w + ci;
        async_copy16(&Ks[0][c * 512], Kb + (size_t)(c * 8 + sIn) * HD + gK);
    }
    {
        const bf16_t* vsrc = Vb + (size_t)(w * 16 + l15) * HD + quad * 8;
        bf16x8 pv0 = *(const bf16x8*)vsrc;
        bf16x8 pv1 = *(const bf16x8*)(vsrc + 32);
        VTRANS(0, pv0, pv1);
    }
    __syncthreads();

    int cur = 0;
    for (int it = 0; it < nIter; ++it) {
        const int nxt = cur ^ 1;
        const bool hn = (it + 1 < nIter);
        bf16x8 av0, av1;
        if (hn) {
            const int s1 = (it + 1) * 64;
            #pragma unroll
            for (int ci = 0; ci < 2; ++ci) {
                const int c = 2 * w + ci;
                async_copy16(&Ks[nxt][c * 512], Kb + (size_t)(s1 + c * 8 + sIn) * HD + gK);
            }
            const bf16_t* vsrc = Vb + (size_t)(s1 + w * 16 + l15) * HD + quad * 8;
            av0 = *(const bf16x8*)vsrc;
            av1 = *(const bf16x8*)(vsrc + 32);
        }
        bf16x8 kb[4][2];
        #pragma unroll
        for (int mt = 0; mt < 4; ++mt)
            #pragma unroll
            for (int kc = 0; kc < 2; ++kc)
                kb[mt][kc] = *(const bf16x8*)&Ks[cur][(mt * 16 + l15) * 64 +
                                                      (((kc * 4 + quad) ^ fK) << 3)];
        const bool skip0 = (it == 2 * j + 1);
        f32x4 zz[2][4];
        __builtin_amdgcn_s_setprio(1);
        #pragma unroll
        for (int mg = 0; mg < 2; ++mg) {
            if (mg == 0 && skip0) continue;
            #pragma unroll
            for (int mt = 0; mt < 4; ++mt) {
                f32x4 z = {};
                z = MFMA16(kb[mt][0], qa[mg][0], z);
                z = MFMA16(kb[mt][1], qa[mg][1], z);
                zz[mg][mt] = z;
            }
        }
        __builtin_amdgcn_s_setprio(0);
        #pragma unroll
        for (int mg = 0; mg < 2; ++mg) {
            if (mg == 0 && skip0) continue;
            const bool diag = (it == 2 * j + mg);
            #pragma unroll
            for (int mt = 0; mt < 4; ++mt) {
                bf16x4 pk;
                #pragma unroll
                for (int r = 0; r < 4; ++r) {
                    float v = zz[mg][mt][r];
                    if (diag && (mt * 16 + quad * 4 + r > w * 16 + l15)) v = -INFINITY;
                    pk[r] = (bf16_t)fast_exp2(v);
                }
                *(bf16x4*)&Ps[w][(mg * 16 + l15) * 72 + mt * 16 + quad * 4] = pk;
            }
        }
        asm volatile("s_waitcnt lgkmcnt(0)" ::: "memory");
        bf16x8 vb[4][2];
        #pragma unroll
        for (int dt = 0; dt < 4; ++dt)
            #pragma unroll
            for (int kc = 0; kc < 2; ++kc)
                vb[dt][kc] = *(const bf16x8*)&Vt[cur][(dt * 16 + l15) * 72 + kc * 32 + quad * 8];
        #pragma unroll
        for (int mg = 0; mg < 2; ++mg) {
            if (mg == 0 && skip0) continue;
            const bf16x8 pa0 = *(const bf16x8*)&Ps[w][(mg * 16 + l15) * 72 + quad * 8];
            const bf16x8 pa1 = *(const bf16x8*)&Ps[w][(mg * 16 + l15) * 72 + 32 + quad * 8];
            __builtin_amdgcn_s_setprio(1);
            #pragma unroll
            for (int dt = 0; dt < 4; ++dt) {
                acco[mg][dt] = MFMA16(pa0, vb[dt][0], acco[mg][dt]);
                acco[mg][dt] = MFMA16(pa1, vb[dt][1], acco[mg][dt]);
            }
            accl[mg] = MFMA16(pa0, ones, accl[mg]);
            accl[mg] = MFMA16(pa1, ones, accl[mg]);
            __builtin_amdgcn_s_setprio(0);
        }
        if (hn) VTRANS(nxt, av0, av1);
        __syncthreads();
        cur = nxt;
    }
    #pragma unroll
    for (int mg = 0; mg < 2; ++mg) {
        #pragma unroll
        for (int r = 0; r < 4; ++r) {
            const float inv = 1.0f / accl[mg][r];
            const int trow = q0 + mg * 64 + w * 16 + quad * 4 + r;
            bf16_t* orow = O + ((size_t)(b * SEQ + trow)) * DIMC + h * HD;
            #pragma unroll
            for (int dt = 0; dt < 4; ++dt)
                orow[dt * 16 + l15] = (bf16_t)(acco[mg][dt][r] * inv);
        }
    }
#undef VTRANS
}

extern "C" void kernel_launch(void* const* d_in, const int* in_sizes, int n_in,
                              void* d_out, int out_size, void* d_ws, size_t ws_size,
                              hipStream_t stream) {
    const float* query = (const float*)d_in[0];
    const float* key = (const float*)d_in[1];
    const float* value = (const float*)d_in[2];
    const float* Wq = (const float*)d_in[3];
    const float* bq = (const float*)d_in[4];
    const float* Wk = (const float*)d_in[5];
    const float* bk = (const float*)d_in[6];
    const float* Wv = (const float*)d_in[7];
    const float* bv = (const float*)d_in[8];
    const float* Wo = (const float*)d_in[9];
    const float* bo = (const float*)d_in[10];

    char* ws = (char*)d_ws;
    const size_t WT_BYTES = (size_t)DIMC * DIMC * sizeof(bf16_t);          // 2 MB
    const size_t ACT_BYTES = (size_t)BATCH * SEQ * DIMC * sizeof(bf16_t);  // 16 MB
    bf16_t* WT = (bf16_t*)ws;  // WqT,WkT,WvT,WoT consecutive (8 MB)
    bf16_t* WoT = WT + 3 * (size_t)DIMC * DIMC;
    float* cosT = (float*)(ws + 4 * WT_BYTES);
    float* sinT = (float*)(ws + 4 * WT_BYTES + 262144);
    bf16_t* Cb = (bf16_t*)(ws + 4 * WT_BYTES + 2 * 262144);  // 3x16 MB bf16 inputs
    bf16_t* Qr = (bf16_t*)((char*)Cb + 3 * ACT_BYTES);
    bf16_t* Kr = (bf16_t*)((char*)Cb + 4 * ACT_BYTES);
    bf16_t* Vr = (bf16_t*)((char*)Cb + 5 * ACT_BYTES);
    bf16_t* Ob = Cb;  // attention output aliases Cq (free after QKV GEMMs)

    transpose_cvt<<<dim3(32, 32, 4), 256, 0, stream>>>(Wq, Wk, Wv, Wo, WT);
    rope_tab<<<dim3(256), 256, 0, stream>>>(cosT, sinT);
    cvt3<<<dim3(4096, 3), 256, 0, stream>>>(query, key, value, Cb);
    gemm_qkv<<<dim3((BATCH * SEQ) / 128, DIMC / 256, 3), 512, 0, stream>>>(
        Cb, WT, bq, bk, bv, Qr, Kr, Vr, cosT, sinT);
    attn_kernel<<<dim3(BATCH * NH, 16), 256, 0, stream>>>(Qr, Kr, Vr, Ob);
    gemm_o<<<dim3((BATCH * SEQ) / 128, DIMC / 256), 512, 0, stream>>>(Ob, WoT, bo, (float*)d_out);
}